// Round 2
// baseline (1514.190 us; speedup 1.0000x reference)
//
#include <hip/hip_runtime.h>
#include <hip/hip_bf16.h>

typedef __attribute__((ext_vector_type(4))) float floatx4;
typedef __attribute__((ext_vector_type(8))) short short8;

static __device__ __forceinline__ float b2f(short s) {
    unsigned int u = ((unsigned int)(unsigned short)s) << 16;
    float f;
    __builtin_memcpy(&f, &u, 4);
    return f;
}
static __device__ __forceinline__ short f2b(float f) {
    __hip_bfloat16 h = __float2bfloat16(f);
    unsigned short u;
    __builtin_memcpy(&u, &h, 2);
    return (short)u;
}

// Writes flag=1 if buffer at `x` (32-bit words, starting at word `off`) looks like
// packed bf16, 0 if fp32. Statistic: bits [14:7] of each word are the low-half bf16's
// exponent (concentrated in [110,140] for normal-ish data) vs uniform fp32 mantissa bits.
__global__ void detect_dtype(const unsigned int* __restrict__ x, int off,
                             int* __restrict__ flag) {
    __shared__ int cnt[256];
    const int tid = threadIdx.x;
    const unsigned int w = x[off + tid];
    const unsigned int e = (w >> 7) & 0xFF;
    cnt[tid] = (e >= 110 && e <= 140) ? 1 : 0;
    __syncthreads();
    for (int s = 128; s > 0; s >>= 1) {
        if (tid < s) cnt[tid] += cnt[tid + s];
        __syncthreads();
    }
    if (tid == 0) *flag = (cnt[0] >= 160) ? 1 : 0;
}

// C[m,n] = sum_k A[m,k]*B[n,k]. 128x128 tile, BK=32, 256 thr (2x2 waves, 4x4 MFMA each).
// A dtype: bf16 if (a_dyn ? *dflag : 1). B dtype: bf16 if *dflag.
// Store: bf16 unless (out_dyn && !*dflag) -> fp32.
__global__ __launch_bounds__(256) void gemm_bt(const void* __restrict__ A,
                                               const void* __restrict__ B,
                                               void* __restrict__ C,
                                               int M, int N, int K,
                                               const int* __restrict__ dflag,
                                               int a_dyn, int out_dyn) {
    constexpr int LDW = 40;  // 32 + 8 pad
    __shared__ short As[128 * LDW];
    __shared__ short Bs[128 * LDW];
    const int isb = *dflag;
    const int a_isb = a_dyn ? isb : 1;
    const int tid = threadIdx.x;
    const int m0 = blockIdx.y * 128, n0 = blockIdx.x * 128;
    const int wave = tid >> 6, lane = tid & 63;
    const int quad = lane >> 4, l16 = lane & 15;
    const int wm = (wave >> 1) * 64, wn = (wave & 1) * 64;
    const int r = tid >> 1, ch = (tid & 1) * 16;
    const size_t arow = (size_t)(m0 + r) * K + ch;
    const size_t brow = (size_t)(n0 + r) * K + ch;
    floatx4 acc[4][4] = {};
    for (int k0 = 0; k0 < K; k0 += 32) {
        short av[16], bv[16];
        if (a_isb) {
            const short* ap = (const short*)A + arow + k0;
            *(short8*)av = *(const short8*)ap;
            *(short8*)(av + 8) = *(const short8*)(ap + 8);
        } else {
            const float* ap = (const float*)A + arow + k0;
            float4 f0 = ((const float4*)ap)[0], f1 = ((const float4*)ap)[1];
            float4 f2 = ((const float4*)ap)[2], f3 = ((const float4*)ap)[3];
            av[0] = f2b(f0.x); av[1] = f2b(f0.y); av[2] = f2b(f0.z); av[3] = f2b(f0.w);
            av[4] = f2b(f1.x); av[5] = f2b(f1.y); av[6] = f2b(f1.z); av[7] = f2b(f1.w);
            av[8] = f2b(f2.x); av[9] = f2b(f2.y); av[10] = f2b(f2.z); av[11] = f2b(f2.w);
            av[12] = f2b(f3.x); av[13] = f2b(f3.y); av[14] = f2b(f3.z); av[15] = f2b(f3.w);
        }
        if (isb) {
            const short* bp = (const short*)B + brow + k0;
            *(short8*)bv = *(const short8*)bp;
            *(short8*)(bv + 8) = *(const short8*)(bp + 8);
        } else {
            const float* bp = (const float*)B + brow + k0;
            float4 f0 = ((const float4*)bp)[0], f1 = ((const float4*)bp)[1];
            float4 f2 = ((const float4*)bp)[2], f3 = ((const float4*)bp)[3];
            bv[0] = f2b(f0.x); bv[1] = f2b(f0.y); bv[2] = f2b(f0.z); bv[3] = f2b(f0.w);
            bv[4] = f2b(f1.x); bv[5] = f2b(f1.y); bv[6] = f2b(f1.z); bv[7] = f2b(f1.w);
            bv[8] = f2b(f2.x); bv[9] = f2b(f2.y); bv[10] = f2b(f2.z); bv[11] = f2b(f2.w);
            bv[12] = f2b(f3.x); bv[13] = f2b(f3.y); bv[14] = f2b(f3.z); bv[15] = f2b(f3.w);
        }
        *(short8*)&As[r * LDW + ch] = *(short8*)av;
        *(short8*)&As[r * LDW + ch + 8] = *(short8*)(av + 8);
        *(short8*)&Bs[r * LDW + ch] = *(short8*)bv;
        *(short8*)&Bs[r * LDW + ch + 8] = *(short8*)(bv + 8);
        __syncthreads();
        short8 af[4], bq[4];
#pragma unroll
        for (int i = 0; i < 4; i++)
            af[i] = *(const short8*)&As[(wm + i * 16 + l16) * LDW + quad * 8];
#pragma unroll
        for (int j = 0; j < 4; j++)
            bq[j] = *(const short8*)&Bs[(wn + j * 16 + l16) * LDW + quad * 8];
#pragma unroll
        for (int i = 0; i < 4; i++)
#pragma unroll
            for (int j = 0; j < 4; j++)
                acc[i][j] = __builtin_amdgcn_mfma_f32_16x16x32_bf16(af[i], bq[j], acc[i][j], 0, 0, 0);
        __syncthreads();
    }
    // C/D layout: col = lane&15, row = quad*4 + reg (m89-verified)
#pragma unroll
    for (int i = 0; i < 4; i++)
#pragma unroll
        for (int j = 0; j < 4; j++)
#pragma unroll
            for (int rr = 0; rr < 4; rr++) {
                const size_t row = m0 + wm + i * 16 + quad * 4 + rr;
                const size_t col = n0 + wn + j * 16 + l16;
                const float v = acc[i][j][rr];
                if (out_dyn && !isb)
                    ((float*)C)[row * N + col] = v;
                else
                    ((short*)C)[row * N + col] = f2b(v);
            }
}

// In-place RoPE on Q [4096 tok x 32 h x 128] and K [4096 tok x 8 h x 128] (both bf16,
// we wrote them). freqs dtype per fflag.
__global__ __launch_bounds__(256) void rope_kernel(short* __restrict__ Qb,
                                                   short* __restrict__ Kb,
                                                   const void* __restrict__ freqs,
                                                   const int* __restrict__ fflag) {
    const int isb = *fflag;
    const int idx = blockIdx.x * 256 + threadIdx.x;
    constexpr int QP = 4096 * 32 * 64;
    short* ptr;
    int t, p;
    if (idx < QP) {
        t = idx >> 11;
        const int rem = idx & 2047;
        p = rem & 63;
        ptr = Qb + (size_t)t * 4096 + (rem >> 6) * 128 + 2 * p;
    } else {
        const int i = idx - QP;
        t = i >> 9;
        const int rem = i & 511;
        p = rem & 63;
        ptr = Kb + (size_t)t * 1024 + (rem >> 6) * 128 + 2 * p;
    }
    const int fi = (t & 1023) * 64 + p;
    const float f = isb ? b2f(((const short*)freqs)[fi]) : ((const float*)freqs)[fi];
    float sv, cv;
    sincosf(f, &sv, &cv);
    const float a = b2f(ptr[0]);
    const float bb = b2f(ptr[1]);
    ptr[0] = f2b(a * cv - bb * sv);
    ptr[1] = f2b(a * sv + bb * cv);
}

// Flash attention, all-bf16 buffers. One block per (batch, q-head, 64-q tile).
__global__ __launch_bounds__(256) void attn_kernel(const short* __restrict__ Q,
                                                   const short* __restrict__ Kc,
                                                   const short* __restrict__ Vc,
                                                   short* __restrict__ AO) {
    constexpr int LQ = 136, LV = 72, LP = 72;
    __shared__ short Qs[64 * LQ];
    __shared__ short Ks[64 * LQ];
    __shared__ short Vts[128 * LV];
    __shared__ short Ps[64 * LP];
    const int tid = threadIdx.x;
    const int qt = blockIdx.x, h = blockIdx.y, b = blockIdx.z;
    const int kvh = h >> 2;
    const size_t tbase = (size_t)b * 1024;
    const int q0 = qt * 64;
    const int wave = tid >> 6, lane = tid & 63;
    const int quad = lane >> 4, l16 = lane & 15;
    const int sr = tid >> 2, sc = (tid & 3) * 32;
    {
        const short* src = Q + (tbase + q0 + sr) * 4096 + h * 128 + sc;
#pragma unroll
        for (int j = 0; j < 4; j++)
            *(short8*)&Qs[sr * LQ + sc + 8 * j] = *(const short8*)(src + 8 * j);
    }
    floatx4 o[8] = {};
    float mrow[4], lrow[4];
#pragma unroll
    for (int rr = 0; rr < 4; rr++) { mrow[rr] = -1.0e30f; lrow[rr] = 0.0f; }
    const float scale = 0.08838834764831845f;
    for (int kt = 0; kt <= qt; kt++) {
        if (kt > 0) __syncthreads();
        {
            const short* ksrc = Kc + (tbase + kt * 64 + sr) * 1024 + kvh * 128 + sc;
#pragma unroll
            for (int j = 0; j < 4; j++)
                *(short8*)&Ks[sr * LQ + sc + 8 * j] = *(const short8*)(ksrc + 8 * j);
            const short* vsrc = Vc + (tbase + kt * 64 + sr) * 1024 + kvh * 128 + sc;
            short vv[32];
#pragma unroll
            for (int j = 0; j < 4; j++)
                *(short8*)(vv + 8 * j) = *(const short8*)(vsrc + 8 * j);
#pragma unroll
            for (int e = 0; e < 32; e++)
                Vts[(sc + e) * LV + sr] = vv[e];
        }
        __syncthreads();
        short8 aq[4];
#pragma unroll
        for (int kk = 0; kk < 4; kk++)
            aq[kk] = *(const short8*)&Qs[(wave * 16 + l16) * LQ + kk * 32 + quad * 8];
        floatx4 s[4];
#pragma unroll
        for (int j = 0; j < 4; j++) {
            floatx4 acc = {};
#pragma unroll
            for (int kk = 0; kk < 4; kk++) {
                short8 bk = *(const short8*)&Ks[(j * 16 + l16) * LQ + kk * 32 + quad * 8];
                acc = __builtin_amdgcn_mfma_f32_16x16x32_bf16(aq[kk], bk, acc, 0, 0, 0);
            }
            s[j] = acc;
        }
        const int qrow = q0 + wave * 16 + quad * 4;
#pragma unroll
        for (int j = 0; j < 4; j++)
#pragma unroll
            for (int rr = 0; rr < 4; rr++) {
                const float v = s[j][rr] * scale;
                const int key = kt * 64 + j * 16 + l16;
                s[j][rr] = (key > qrow + rr) ? -1.0e9f : v;
            }
        float alpha[4];
#pragma unroll
        for (int rr = 0; rr < 4; rr++) {
            float mx = fmaxf(fmaxf(s[0][rr], s[1][rr]), fmaxf(s[2][rr], s[3][rr]));
#pragma unroll
            for (int off = 1; off < 16; off <<= 1)
                mx = fmaxf(mx, __shfl_xor(mx, off, 64));
            const float mnew = fmaxf(mrow[rr], mx);
            alpha[rr] = __expf(mrow[rr] - mnew);
            float rsum = 0.0f;
#pragma unroll
            for (int j = 0; j < 4; j++) {
                const float p = __expf(s[j][rr] - mnew);
                s[j][rr] = p;
                rsum += p;
            }
#pragma unroll
            for (int off = 1; off < 16; off <<= 1)
                rsum += __shfl_xor(rsum, off, 64);
            lrow[rr] = lrow[rr] * alpha[rr] + rsum;
            mrow[rr] = mnew;
        }
#pragma unroll
        for (int c = 0; c < 8; c++)
#pragma unroll
            for (int rr = 0; rr < 4; rr++)
                o[c][rr] *= alpha[rr];
#pragma unroll
        for (int j = 0; j < 4; j++)
#pragma unroll
            for (int rr = 0; rr < 4; rr++)
                Ps[(wave * 16 + quad * 4 + rr) * LP + j * 16 + l16] = f2b(s[j][rr]);
        __syncthreads();
        short8 ap[2];
        ap[0] = *(const short8*)&Ps[(wave * 16 + l16) * LP + quad * 8];
        ap[1] = *(const short8*)&Ps[(wave * 16 + l16) * LP + 32 + quad * 8];
#pragma unroll
        for (int c = 0; c < 8; c++) {
#pragma unroll
            for (int kk = 0; kk < 2; kk++) {
                short8 bv = *(const short8*)&Vts[(c * 16 + l16) * LV + kk * 32 + quad * 8];
                o[c] = __builtin_amdgcn_mfma_f32_16x16x32_bf16(ap[kk], bv, o[c], 0, 0, 0);
            }
        }
    }
    float invl[4];
#pragma unroll
    for (int rr = 0; rr < 4; rr++) invl[rr] = 1.0f / lrow[rr];
#pragma unroll
    for (int c = 0; c < 8; c++)
#pragma unroll
        for (int rr = 0; rr < 4; rr++) {
            const size_t row = tbase + q0 + wave * 16 + quad * 4 + rr;
            AO[row * 4096 + h * 128 + c * 16 + l16] = f2b(o[c][rr] * invl[rr]);
        }
}

extern "C" void kernel_launch(void* const* d_in, const int* in_sizes, int n_in,
                              void* d_out, int out_size, void* d_ws, size_t ws_size,
                              hipStream_t stream) {
    // inputs: x, wq, wk, wv, wo, freqs, mask(unused), starting_pos(unused)
    const void* x     = d_in[0];
    const void* wq    = d_in[1];
    const void* wk    = d_in[2];
    const void* wv    = d_in[3];
    const void* wo    = d_in[4];
    const void* freqs = d_in[5];
    char* ws = (char*)d_ws;
    int* flag = (int*)ws;                               // flag[0]: x/weights, flag[1]: freqs
    short* Kb = (short*)(ws + 256);                     // 4096x1024 bf16 = 8388608 B
    short* Vb = (short*)(ws + 256 + 8388608);           // 4096x1024 bf16 = 8388608 B
    short* AO = (short*)(ws + 256 + 16777216);          // 4096x4096 bf16 = 33554432 B
    short* Qb = (short*)d_out;                          // Q scratch lives in d_out (dead
                                                        // before final GEMM overwrites it)

    detect_dtype<<<1, 256, 0, stream>>>((const unsigned int*)x, 0, flag);
    detect_dtype<<<1, 256, 0, stream>>>((const unsigned int*)freqs, 100, flag + 1);
    gemm_bt<<<dim3(32, 32), 256, 0, stream>>>(x, wq, Qb, 4096, 4096, 4096, flag, 1, 0);
    gemm_bt<<<dim3(8, 32), 256, 0, stream>>>(x, wk, Kb, 4096, 1024, 4096, flag, 1, 0);
    gemm_bt<<<dim3(8, 32), 256, 0, stream>>>(x, wv, Vb, 4096, 1024, 4096, flag, 1, 0);
    rope_kernel<<<40960, 256, 0, stream>>>(Qb, Kb, freqs, flag + 1);
    attn_kernel<<<dim3(16, 32, 4), 256, 0, stream>>>(Qb, Kb, Vb, AO);
    gemm_bt<<<dim3(32, 32), 256, 0, stream>>>(AO, wo, d_out, 4096, 4096, 4096, flag, 0, 1);
}